// Round 3
// baseline (14063.176 us; speedup 1.0000x reference)
//
#include <hip/hip_runtime.h>
#include <hip/hip_cooperative_groups.h>
#include <cmath>

namespace cg = cooperative_groups;

namespace {
constexpr int kB = 32, kT = 128, kD = 512, kH = 1024, kE = 8;
constexpr int kG4 = 4 * kH;   // 4096 gate rows per expert
constexpr int kKV = kH + kD;  // 1536
constexpr int kBlocks = 256;  // 8 experts x 32 unit-blocks (32 units each)
constexpr int kThreads = 512; // 8 waves: (gate g, half sub) = (w&3, w>>2)

struct Ws {
  float c[kB][kH];
};

__device__ __forceinline__ float sigmoidf_(float v) { return 1.0f / (1.0f + expf(-v)); }
}  // namespace

// Block bid: e = bid>>5, jb = bid&31 -> units j0=jb*32..+31 of expert e.
// Wave w: gate g = w&3, sub = w>>2 -> 16 gate-rows (units j0+sub*16..+15).
// Every block replicates the per-batch expert selection (identical FP order on
// all blocks -> identical argmax everywhere; no cross-block sel traffic).
__global__ __launch_bounds__(512, 2) void k_step(
    const float* __restrict__ x, const float* __restrict__ Wih,
    const float* __restrict__ Whh, const float* __restrict__ bih,
    const float* __restrict__ bhh, const float* __restrict__ selW,
    const float* __restrict__ selb, float* __restrict__ out,
    Ws* __restrict__ ws, int t0, int t1, int coop) {
  const int bid = blockIdx.x;
  const int e = bid >> 5, jb = bid & 31;
  const int j0 = jb * 32;
  const int tid = threadIdx.x;
  const int w = tid >> 6, lane = tid & 63;
  const int g = w & 3, sub = w >> 2;

  __shared__ float v[8][kKV];    // 48 KB staged [h, x] for up to 8 batch rows
  __shared__ float gl[8][128];   // 4 KB gates: [bi][g*32 + local_j]
  __shared__ int bl[kB];
  __shared__ int s_cnt;
  __shared__ int sel_sh[kB];

  // Pin rows rr=0..3 of this wave's 16 rows in VGPRs for the whole run.
  float4 pin[24];
#pragma unroll
  for (int r = 0; r < 4; ++r) {
    const size_t gr = (size_t)e * kG4 + (size_t)g * kH + j0 + sub * 16 + r;
    const float4* whp = reinterpret_cast<const float4*>(Whh + gr * kH);
    const float4* wip = reinterpret_cast<const float4*>(Wih + gr * kD);
#pragma unroll
    for (int ii = 0; ii < 4; ++ii) pin[r * 6 + ii] = whp[lane + 64 * ii];
#pragma unroll
    for (int ii = 0; ii < 2; ++ii) pin[r * 6 + 4 + ii] = wip[lane + 64 * ii];
  }

  for (int t = t0; t < t1; ++t) {
    // ---- replicated expert selection ----
    if (t > 0) {
      const int b = tid >> 4, s = tid & 15;  // 32 rows x 16 threads
      const float4* hp = reinterpret_cast<const float4*>(out + ((size_t)b * kT + (t - 1)) * kH);
      const float4* xp = reinterpret_cast<const float4*>(x + ((size_t)b * kT + t) * kD);
      const float4* swp = reinterpret_cast<const float4*>(selW);
      float acc[kE];
#pragma unroll
      for (int ee = 0; ee < kE; ++ee) acc[ee] = 0.0f;
      for (int i4 = s; i4 < 384; i4 += 16) {  // kKV/4 = 384 float4 positions
        const float4 vv = (i4 < 256) ? hp[i4] : xp[i4 - 256];
#pragma unroll
        for (int ee = 0; ee < kE; ++ee) {
          const float4 wv = swp[ee * 384 + i4];
          acc[ee] += vv.x * wv.x + vv.y * wv.y + vv.z * wv.z + vv.w * wv.w;
        }
      }
#pragma unroll
      for (int ee = 0; ee < kE; ++ee) {
        acc[ee] += __shfl_xor(acc[ee], 1, 64);
        acc[ee] += __shfl_xor(acc[ee], 2, 64);
        acc[ee] += __shfl_xor(acc[ee], 4, 64);
        acc[ee] += __shfl_xor(acc[ee], 8, 64);
      }
      if (s == 0) {
        float best = acc[0] + selb[0];
        int bs = 0;
#pragma unroll
        for (int ee = 1; ee < kE; ++ee) {
          const float l = acc[ee] + selb[ee];
          if (l > best) { best = l; bs = ee; }  // strict > == first-max (jnp.argmax)
        }
        sel_sh[b] = bs;
      }
    }
    __syncthreads();

    if (tid == 0) {
      int c = 0;
      if (t == 0) {
        if (e == 0)
          for (int b2 = 0; b2 < kB; ++b2) bl[c++] = b2;  // step 0: expert 0
      } else {
        for (int b2 = 0; b2 < kB; ++b2)
          if (sel_sh[b2] == e) bl[c++] = b2;
      }
      s_cnt = c;
    }
    __syncthreads();
    const int cnt = s_cnt;

    auto compute_iter = [&](const float4 (&wv)[24], int r0, int nb) {
      for (int bi = 0; bi < nb; ++bi) {
        const float4* vh = reinterpret_cast<const float4*>(&v[bi][0]);
        const float4* vx = reinterpret_cast<const float4*>(&v[bi][kH]);
        float a[4] = {0.f, 0.f, 0.f, 0.f};
        if (t > 0) {
#pragma unroll
          for (int ii = 0; ii < 4; ++ii) {
            const float4 bv = vh[lane + 64 * ii];
#pragma unroll
            for (int r = 0; r < 4; ++r)
              a[r] += wv[r * 6 + ii].x * bv.x + wv[r * 6 + ii].y * bv.y +
                      wv[r * 6 + ii].z * bv.z + wv[r * 6 + ii].w * bv.w;
          }
        }
#pragma unroll
        for (int ii = 0; ii < 2; ++ii) {
          const float4 bv = vx[lane + 64 * ii];
#pragma unroll
          for (int r = 0; r < 4; ++r)
            a[r] += wv[r * 6 + 4 + ii].x * bv.x + wv[r * 6 + 4 + ii].y * bv.y +
                    wv[r * 6 + 4 + ii].z * bv.z + wv[r * 6 + 4 + ii].w * bv.w;
        }
#pragma unroll
        for (int r = 0; r < 4; ++r) {
#pragma unroll
          for (int off = 32; off > 0; off >>= 1) a[r] += __shfl_xor(a[r], off, 64);
        }
        if (lane == 0) {
#pragma unroll
          for (int r = 0; r < 4; ++r) {
            const size_t gr = (size_t)e * kG4 + (size_t)g * kH + j0 + sub * 16 + r0 + r;
            gl[bi][g * 32 + sub * 16 + r0 + r] = a[r] + bih[gr] + bhh[gr];
          }
        }
      }
    };

#pragma unroll 1
    for (int c0 = 0; c0 < cnt; c0 += 8) {
      const int nb = min(8, cnt - c0);
      if (t > 0) {
        for (int idx = tid; idx < nb * 384; idx += kThreads) {
          const int bi = idx / 384, i4 = idx - bi * 384;
          const int b2 = bl[c0 + bi];
          const float4 vv =
              (i4 < 256)
                  ? reinterpret_cast<const float4*>(out + ((size_t)b2 * kT + (t - 1)) * kH)[i4]
                  : reinterpret_cast<const float4*>(x + ((size_t)b2 * kT + t) * kD)[i4 - 256];
          reinterpret_cast<float4*>(&v[bi][0])[i4] = vv;
        }
      } else {
        for (int idx = tid; idx < nb * 128; idx += kThreads) {
          const int bi = idx / 128, i4 = idx - bi * 128;
          const int b2 = bl[c0 + bi];
          reinterpret_cast<float4*>(&v[bi][kH])[i4] =
              reinterpret_cast<const float4*>(x + (size_t)b2 * kT * kD)[i4];
        }
      }
      __syncthreads();

      compute_iter(pin, 0, nb);
#pragma unroll 1
      for (int it = 1; it < 4; ++it) {
        float4 wst[24];
        const int r0 = it * 4;
#pragma unroll
        for (int r = 0; r < 4; ++r) {
          const size_t gr = (size_t)e * kG4 + (size_t)g * kH + j0 + sub * 16 + r0 + r;
          const float4* whp = reinterpret_cast<const float4*>(Whh + gr * kH);
          const float4* wip = reinterpret_cast<const float4*>(Wih + gr * kD);
          if (t > 0) {
#pragma unroll
            for (int ii = 0; ii < 4; ++ii) wst[r * 6 + ii] = whp[lane + 64 * ii];
          }
#pragma unroll
          for (int ii = 0; ii < 2; ++ii) wst[r * 6 + 4 + ii] = wip[lane + 64 * ii];
        }
        compute_iter(wst, r0, nb);
      }
      __syncthreads();

      if (tid < nb * 32) {
        const int bi = tid >> 5, lj = tid & 31;
        const int b2 = bl[c0 + bi], j = j0 + lj;
        const float gi = gl[bi][0 * 32 + lj];
        const float gf = gl[bi][1 * 32 + lj];
        const float gg = gl[bi][2 * 32 + lj];
        const float go = gl[bi][3 * 32 + lj];
        const float c_old = (t > 0) ? ws->c[b2][j] : 0.0f;
        const float c_new = sigmoidf_(gf) * c_old + sigmoidf_(gi) * tanhf(gg);
        const float h_new = sigmoidf_(go) * tanhf(c_new);
        ws->c[b2][j] = c_new;
        out[((size_t)b2 * kT + t) * kH + j] = h_new;
      }
      __syncthreads();
    }

    if (coop && t + 1 < t1) {
      __threadfence();
      cg::this_grid().sync();
      __threadfence();
    }
  }
}

extern "C" void kernel_launch(void* const* d_in, const int* in_sizes, int n_in,
                              void* d_out, int out_size, void* d_ws, size_t ws_size,
                              hipStream_t stream) {
  const float* x    = (const float*)d_in[0];
  const float* Wih  = (const float*)d_in[1];
  const float* Whh  = (const float*)d_in[2];
  const float* bih  = (const float*)d_in[3];
  const float* bhh  = (const float*)d_in[4];
  const float* selW = (const float*)d_in[5];
  const float* selb = (const float*)d_in[6];
  float* out = (float*)d_out;
  Ws* ws = (Ws*)d_ws;

  // Cooperative path needs all 256 blocks co-resident; verify, else fall back
  // to per-step launches of the SAME kernel (bit-identical math either way).
  int perCU = 0;
  (void)hipOccupancyMaxActiveBlocksPerMultiprocessor(&perCU, k_step, kThreads, 0);
  int dev = 0, numCU = 0;
  (void)hipGetDevice(&dev);
  (void)hipDeviceGetAttribute(&numCU, hipDeviceAttributeMultiprocessorCount, dev);

  bool done = false;
  if (perCU > 0 && perCU * numCU >= kBlocks) {
    int t0 = 0, t1 = kT, coop = 1;
    void* args[] = {(void*)&x, (void*)&Wih, (void*)&Whh, (void*)&bih, (void*)&bhh,
                    (void*)&selW, (void*)&selb, (void*)&out, (void*)&ws,
                    (void*)&t0, (void*)&t1, (void*)&coop};
    hipError_t err = hipLaunchCooperativeKernel((const void*)k_step, dim3(kBlocks),
                                                dim3(kThreads), args, 0, stream);
    done = (err == hipSuccess);
  }
  if (!done) {
    for (int t = 0; t < kT; ++t) {
      k_step<<<dim3(kBlocks), dim3(kThreads), 0, stream>>>(
          x, Wih, Whh, bih, bhh, selW, selb, out, ws, t, t + 1, 0);
    }
  }
}

// Round 4
// 11364.046 us; speedup vs baseline: 1.2375x; 1.2375x over previous
//
#include <hip/hip_runtime.h>
#include <hip/hip_cooperative_groups.h>
#include <cmath>

namespace cg = cooperative_groups;

namespace {
constexpr int kB = 32, kT = 128, kD = 512, kH = 1024, kE = 8;
constexpr int kG4 = 4 * kH;     // 4096 gate rows per expert
constexpr int kKV = kH + kD;    // 1536
constexpr int kCellBlocks = 512;  // 8 experts x 64 unit-blocks (16 units each)
constexpr int kThreads = 256;     // 4 waves = 4 gates
constexpr int kNB = 8;            // batch rows staged per chunk

struct Ws {
  float c[kB][kH];
  float logits[kB][kE];
};

__device__ __forceinline__ float sigmoidf_(float v) { return 1.0f / (1.0f + expf(-v)); }

// ---- logits[b][e] for step t (needs full h_{t-1}) ----
__device__ __forceinline__ void dev_logits(const float* __restrict__ x,
                                           const float* __restrict__ selW,
                                           const float* __restrict__ selb,
                                           const float* __restrict__ out,
                                           Ws* __restrict__ ws, int t, int bid,
                                           int tid, float* red) {
  const int b = bid >> 3, e = bid & 7;
  const float4* hp = reinterpret_cast<const float4*>(out + ((size_t)b * kT + (t - 1)) * kH);
  const float4* xp = reinterpret_cast<const float4*>(x + ((size_t)b * kT + t) * kD);
  const float4* wp = reinterpret_cast<const float4*>(selW + (size_t)e * kKV);
  float acc = 0.0f;
  for (int i = tid; i < 384; i += kThreads) {  // kKV/4
    const float4 vv = (i < 256) ? hp[i] : xp[i - 256];
    const float4 wv = wp[i];
    acc += vv.x * wv.x + vv.y * wv.y + vv.z * wv.z + vv.w * wv.w;
  }
#pragma unroll
  for (int off = 32; off > 0; off >>= 1) acc += __shfl_xor(acc, off, 64);
  if ((tid & 63) == 0) red[tid >> 6] = acc;
  __syncthreads();
  if (tid == 0) ws->logits[b][e] = red[0] + red[1] + red[2] + red[3] + selb[e];
}

// ---- gate GEMV chunk: 16 rows (gate g), NB staged batch rows ----
template <int NB>
__device__ __forceinline__ void cell_chunk(const float* __restrict__ Wih,
                                           const float* __restrict__ Whh,
                                           const float* __restrict__ bih,
                                           const float* __restrict__ bhh,
                                           const float (*v)[kKV], float (*gl)[64],
                                           int e, int g, int j0, int lane) {
#pragma unroll 1
  for (int grp = 0; grp < 4; ++grp) {  // 4 groups of 4 rows
    const int r0 = grp * 4;
    float4 w[4][6];
#pragma unroll
    for (int r = 0; r < 4; ++r) {
      const size_t gr = ((size_t)e * 4 + g) * kH + j0 + r0 + r;
      const float4* whp = reinterpret_cast<const float4*>(Whh + gr * kH);
      const float4* wip = reinterpret_cast<const float4*>(Wih + gr * kD);
#pragma unroll
      for (int ii = 0; ii < 4; ++ii) w[r][ii] = whp[lane + 64 * ii];
#pragma unroll
      for (int ii = 0; ii < 2; ++ii) w[r][4 + ii] = wip[lane + 64 * ii];
    }
    float a[4][NB];
#pragma unroll
    for (int r = 0; r < 4; ++r)
#pragma unroll
      for (int bi = 0; bi < NB; ++bi) a[r][bi] = 0.0f;
#pragma unroll
    for (int bi = 0; bi < NB; ++bi) {
      const float4* vp = reinterpret_cast<const float4*>(&v[bi][0]);
#pragma unroll
      for (int ii = 0; ii < 6; ++ii) {
        const int idx = (ii < 4) ? (lane + 64 * ii) : (256 + lane + 64 * (ii - 4));
        const float4 bv = vp[idx];
#pragma unroll
        for (int r = 0; r < 4; ++r)
          a[r][bi] += w[r][ii].x * bv.x + w[r][ii].y * bv.y +
                      w[r][ii].z * bv.z + w[r][ii].w * bv.w;
      }
    }
#pragma unroll
    for (int r = 0; r < 4; ++r)
#pragma unroll
      for (int bi = 0; bi < NB; ++bi) {
#pragma unroll
        for (int off = 32; off > 0; off >>= 1) a[r][bi] += __shfl_xor(a[r][bi], off, 64);
      }
    if (lane == 0) {
#pragma unroll
      for (int r = 0; r < 4; ++r) {
        const size_t gr = ((size_t)e * 4 + g) * kH + j0 + r0 + r;
        const float bsum = bih[gr] + bhh[gr];
#pragma unroll
        for (int bi = 0; bi < NB; ++bi) gl[bi][g * 16 + r0 + r] = a[r][bi] + bsum;
      }
    }
  }
}

__device__ void dev_cell(const float* __restrict__ x, const float* __restrict__ Wih,
                         const float* __restrict__ Whh, const float* __restrict__ bih,
                         const float* __restrict__ bhh, float* __restrict__ out,
                         Ws* __restrict__ ws, int t, int bid, int tid,
                         float (*v)[kKV], float (*gl)[64], int* bl, int* s_cnt_p) {
  const int e = bid >> 6, jb = bid & 63;
  const int j0 = jb * 16;
  const int g = tid >> 6, lane = tid & 63;

  if (tid == 0) {  // replicated tiny argmax from precomputed logits
    int c = 0;
    for (int b = 0; b < kB; ++b) {
      int bs = 0;
      if (t > 0) {
        float best = ws->logits[b][0];
#pragma unroll
        for (int ee = 1; ee < kE; ++ee) {
          const float l = ws->logits[b][ee];
          if (l > best) { best = l; bs = ee; }  // strict > == first-max (jnp.argmax)
        }
      }
      if (bs == e) bl[c++] = b;
    }
    *s_cnt_p = c;
  }
  __syncthreads();
  const int cnt = *s_cnt_p;
  if (cnt == 0) return;

  for (int c0 = 0; c0 < cnt; c0 += kNB) {
    const int nb = (cnt - c0 < kNB) ? (cnt - c0) : kNB;
    // stage v = [h_{t-1} | x_t] (h-part zero at t==0)
    for (int idx = tid; idx < nb * 384; idx += kThreads) {
      const int bi = idx / 384, i4 = idx - bi * 384;
      const int b = bl[c0 + bi];
      float4 vv;
      if (i4 < 256) {
        vv = (t > 0)
                 ? reinterpret_cast<const float4*>(out + ((size_t)b * kT + (t - 1)) * kH)[i4]
                 : make_float4(0.f, 0.f, 0.f, 0.f);
      } else {
        vv = reinterpret_cast<const float4*>(x + ((size_t)b * kT + t) * kD)[i4 - 256];
      }
      reinterpret_cast<float4*>(&v[bi][0])[i4] = vv;
    }
    __syncthreads();

    const int nbr = (nb >= 7) ? 8 : (nb >= 5) ? 6 : (nb >= 3) ? 4 : nb;
    switch (nbr) {
      case 1: cell_chunk<1>(Wih, Whh, bih, bhh, v, gl, e, g, j0, lane); break;
      case 2: cell_chunk<2>(Wih, Whh, bih, bhh, v, gl, e, g, j0, lane); break;
      case 4: cell_chunk<4>(Wih, Whh, bih, bhh, v, gl, e, g, j0, lane); break;
      case 6: cell_chunk<6>(Wih, Whh, bih, bhh, v, gl, e, g, j0, lane); break;
      default: cell_chunk<8>(Wih, Whh, bih, bhh, v, gl, e, g, j0, lane); break;
    }
    __syncthreads();

    if (tid < nb * 16) {
      const int bi = tid >> 4, u = tid & 15;
      const int b = bl[c0 + bi], j = j0 + u;
      const float gi = gl[bi][0 * 16 + u];
      const float gf = gl[bi][1 * 16 + u];
      const float gg = gl[bi][2 * 16 + u];
      const float go = gl[bi][3 * 16 + u];
      const float c_old = (t > 0) ? ws->c[b][j] : 0.0f;
      const float c_new = sigmoidf_(gf) * c_old + sigmoidf_(gi) * tanhf(gg);
      const float h_new = sigmoidf_(go) * tanhf(c_new);
      ws->c[b][j] = c_new;
      out[((size_t)b * kT + t) * kH + j] = h_new;
    }
    __syncthreads();
  }
}
}  // namespace

__global__ __launch_bounds__(kThreads, 2) void k_fused(
    const float* __restrict__ x, const float* __restrict__ Wih,
    const float* __restrict__ Whh, const float* __restrict__ bih,
    const float* __restrict__ bhh, const float* __restrict__ selW,
    const float* __restrict__ selb, float* __restrict__ out, Ws* ws) {
  cg::grid_group grid = cg::this_grid();
  __shared__ float v[kNB][kKV];
  __shared__ float gl[kNB][64];
  __shared__ int bl[kB];
  __shared__ int s_cnt;
  __shared__ float red[4];
  const int bid = blockIdx.x, tid = threadIdx.x;

  for (int t = 0; t < kT; ++t) {
    if (t > 0) {
      if (bid < kB * kE) dev_logits(x, selW, selb, out, ws, t, bid, tid, red);
      __threadfence();
      grid.sync();
    }
    dev_cell(x, Wih, Whh, bih, bhh, out, ws, t, bid, tid, v, gl, bl, &s_cnt);
    if (t + 1 < kT) {
      __threadfence();
      grid.sync();
    }
  }
}

__global__ __launch_bounds__(kThreads) void k_logits(
    const float* __restrict__ x, const float* __restrict__ selW,
    const float* __restrict__ selb, const float* __restrict__ out, Ws* ws, int t) {
  __shared__ float red[4];
  dev_logits(x, selW, selb, out, ws, t, blockIdx.x, threadIdx.x, red);
}

__global__ __launch_bounds__(kThreads) void k_cell(
    const float* __restrict__ x, const float* __restrict__ Wih,
    const float* __restrict__ Whh, const float* __restrict__ bih,
    const float* __restrict__ bhh, float* __restrict__ out, Ws* ws, int t) {
  __shared__ float v[kNB][kKV];
  __shared__ float gl[kNB][64];
  __shared__ int bl[kB];
  __shared__ int s_cnt;
  dev_cell(x, Wih, Whh, bih, bhh, out, ws, t, blockIdx.x, threadIdx.x, v, gl, bl, &s_cnt);
}

extern "C" void kernel_launch(void* const* d_in, const int* in_sizes, int n_in,
                              void* d_out, int out_size, void* d_ws, size_t ws_size,
                              hipStream_t stream) {
  const float* x    = (const float*)d_in[0];
  const float* Wih  = (const float*)d_in[1];
  const float* Whh  = (const float*)d_in[2];
  const float* bih  = (const float*)d_in[3];
  const float* bhh  = (const float*)d_in[4];
  const float* selW = (const float*)d_in[5];
  const float* selb = (const float*)d_in[6];
  float* out = (float*)d_out;
  Ws* ws = (Ws*)d_ws;

  int perCU = 0;
  (void)hipOccupancyMaxActiveBlocksPerMultiprocessor(&perCU, k_fused, kThreads, 0);
  int dev = 0, numCU = 0;
  (void)hipGetDevice(&dev);
  (void)hipDeviceGetAttribute(&numCU, hipDeviceAttributeMultiprocessorCount, dev);

  bool done = false;
  if (perCU > 0 && perCU * numCU >= kCellBlocks) {
    void* args[] = {(void*)&x, (void*)&Wih, (void*)&Whh, (void*)&bih, (void*)&bhh,
                    (void*)&selW, (void*)&selb, (void*)&out, (void*)&ws};
    hipError_t err = hipLaunchCooperativeKernel((const void*)k_fused, dim3(kCellBlocks),
                                                dim3(kThreads), args, 0, stream);
    done = (err == hipSuccess);
  }
  if (!done) {  // same math, per-step launches
    for (int t = 0; t < kT; ++t) {
      if (t > 0) k_logits<<<dim3(kB * kE), dim3(kThreads), 0, stream>>>(x, selW, selb, out, ws, t);
      k_cell<<<dim3(kCellBlocks), dim3(kThreads), 0, stream>>>(x, Wih, Whh, bih, bhh, out, ws, t);
    }
  }
}